// Round 5
// baseline (293.516 us; speedup 1.0000x reference)
//
#include <hip/hip_runtime.h>
#include <hip/hip_bf16.h>
#include <math.h>

#define N_NODES 50000
#define N_EDGES 1600000
#define IN_CH   128
#define OUT_CH  64
#define N_HEADS 4
#define CH      (N_HEADS * OUT_CH)   // 256

#define NPB   64                     // nodes per bin
#define BINS  782                    // ceil(50000/64)
#define CAPB  3072                   // per-bin edge capacity (avg 2048)
#define CHUNK 8000                   // edges per bin_scatter block

typedef __attribute__((ext_vector_type(8))) short bf16x8;
typedef __attribute__((ext_vector_type(4))) float f32x4;

// ---------- helpers ----------
__device__ __forceinline__ float bf16_lo(unsigned u) { return __uint_as_float(u << 16); }
__device__ __forceinline__ float bf16_hi(unsigned u) { return __uint_as_float(u & 0xffff0000u); }
__device__ __forceinline__ unsigned short f_to_bf16(float f) {
  unsigned u = __float_as_uint(f);
  u += 0x7fffu + ((u >> 16) & 1u);   // RNE
  return (unsigned short)(u >> 16);
}

// ---------- kernel 0: prep = W swizzle (A-fragment order) + cursor init ----------
// A-frag layout (16x16x32, A[m][k]): m = lane&15 = channel-in-block, k = (lane>>4)*8 + j.
// wb2[((mb*4 + kc)*64 + lane)*8 + j] = bf16(W[h][kc*32 + (lane>>4)*8 + j][o]),
//   ch = mb*16 + (lane&15), h = ch>>6, o = ch&63.
__global__ __launch_bounds__(256) void prep_kernel(
    const float* __restrict__ w, unsigned short* __restrict__ wb2,
    int* __restrict__ gcur)
{
  if (blockIdx.x < 128) {
    int i = blockIdx.x * 256 + threadIdx.x;        // 32768 total
    int j = i & 7, lane = (i >> 3) & 63, kc = (i >> 9) & 3, mb = i >> 11;
    int k = kc * 32 + (lane >> 4) * 8 + j;
    int ch = mb * 16 + (lane & 15);
    int h = ch >> 6, o = ch & 63;
    wb2[i] = f_to_bf16(w[(h * IN_CH + k) * OUT_CH + o]);
  } else {
    for (int b = threadIdx.x; b < BINS; b += 256) gcur[b] = b * CAPB;
  }
}

// ---------- kernel 1: MFMA GEMM, swapped operands: D[ch][node] ----------
// block 256 = 4 waves; wave = 32 nodes (2 tiles of 16) x 256 channels.
// Lane l16 owns one node per tile -> register-direct coalesced epilogue.
__global__ __launch_bounds__(256) void gemm_mfma(
    const float* __restrict__ x, const unsigned short* __restrict__ wb2,
    const float* __restrict__ aw,
    unsigned short* __restrict__ xmsg, float* __restrict__ sbuf, float* __restrict__ tbuf)
{
  const int lane = threadIdx.x & 63;
  const int wv   = threadIdx.x >> 6;
  const int q    = lane >> 4;
  const int l16  = lane & 15;
  const int nb   = blockIdx.x * 128 + wv * 32;     // wave's 32 nodes

  // B-frags: B[k][n], n = l16 (node), k = q*8+j
  bf16x8 bfrag[2][4];
  #pragma unroll
  for (int t = 0; t < 2; ++t) {
    int node = min(nb + t * 16 + l16, N_NODES - 1);
    const float* xp = x + (size_t)node * IN_CH + q * 8;
    #pragma unroll
    for (int kc = 0; kc < 4; ++kc) {
      f32x4 lo = *(const f32x4*)(xp + kc * 32);
      f32x4 hi = *(const f32x4*)(xp + kc * 32 + 4);
      bf16x8 b;
      b[0] = (short)f_to_bf16(lo[0]); b[1] = (short)f_to_bf16(lo[1]);
      b[2] = (short)f_to_bf16(lo[2]); b[3] = (short)f_to_bf16(lo[3]);
      b[4] = (short)f_to_bf16(hi[0]); b[5] = (short)f_to_bf16(hi[1]);
      b[6] = (short)f_to_bf16(hi[2]); b[7] = (short)f_to_bf16(hi[3]);
      bfrag[t][kc] = b;
    }
  }

  f32x4 acc[2][16];
  #pragma unroll
  for (int t = 0; t < 2; ++t)
    #pragma unroll
    for (int mb = 0; mb < 16; ++mb)
      acc[t][mb] = (f32x4){0.f, 0.f, 0.f, 0.f};

  #pragma unroll
  for (int kc = 0; kc < 4; ++kc) {
    #pragma unroll
    for (int mb = 0; mb < 16; ++mb) {
      bf16x8 a = *(const bf16x8*)(wb2 + ((size_t)(mb * 4 + kc) * 64 + lane) * 8);
      acc[0][mb] = __builtin_amdgcn_mfma_f32_16x16x32_bf16(a, bfrag[0][kc], acc[0][mb], 0, 0, 0);
      acc[1][mb] = __builtin_amdgcn_mfma_f32_16x16x32_bf16(a, bfrag[1][kc], acc[1][mb], 0, 0, 0);
    }
  }

  // epilogue: lane owns node (l16) x channels {mb*16 + q*4 + reg}
  #pragma unroll
  for (int t = 0; t < 2; ++t) {
    const int node = nb + t * 16 + l16;
    const bool valid = node < N_NODES;

    float sv[4] = {0.f, 0.f, 0.f, 0.f};
    float tv[4] = {0.f, 0.f, 0.f, 0.f};
    #pragma unroll
    for (int mb = 0; mb < 16; ++mb) {
      // xmsg store: 4 consecutive channels, 8B
      ushort4 pk;
      pk.x = f_to_bf16(acc[t][mb][0]); pk.y = f_to_bf16(acc[t][mb][1]);
      pk.z = f_to_bf16(acc[t][mb][2]); pk.w = f_to_bf16(acc[t][mb][3]);
      if (valid)
        *(ushort4*)(xmsg + (size_t)node * CH + mb * 16 + q * 4) = pk;

      const int h = mb >> 2;
      const int o = (mb & 3) * 16 + q * 4;
      #pragma unroll
      for (int reg = 0; reg < 4; ++reg) {
        float as_ = aw[h * 128 + o + reg];
        float at_ = aw[h * 128 + 64 + o + reg];
        sv[h] += acc[t][mb][reg] * as_;
        tv[h] += acc[t][mb][reg] * at_;
      }
    }
    // reduce over q-lanes (xor 16, 32 keep l16 fixed)
    #pragma unroll
    for (int hh = 0; hh < 4; ++hh) {
      sv[hh] += __shfl_xor(sv[hh], 16); sv[hh] += __shfl_xor(sv[hh], 32);
      tv[hh] += __shfl_xor(tv[hh], 16); tv[hh] += __shfl_xor(tv[hh], 32);
    }
    float svq = (q == 0) ? sv[0] : (q == 1) ? sv[1] : (q == 2) ? sv[2] : sv[3];
    float tvq = (q == 0) ? tv[0] : (q == 1) ? tv[1] : (q == 2) ? tv[2] : tv[3];
    if (valid) {
      sbuf[node * 4 + q] = svq;
      tbuf[node * 4 + q] = tvq;
    }
  }
}

// ---------- kernel 2a: binned ranked scatter ----------
__global__ __launch_bounds__(256) void bin_scatter(
    const int* __restrict__ etgt, const int* __restrict__ esrc,
    const float* __restrict__ eval, int* __restrict__ gcur, int2* __restrict__ binned)
{
  __shared__ int lhist[BINS];
  __shared__ int lbase[BINS];
  __shared__ unsigned short stg[CHUNK];

  const int tid = threadIdx.x;
  const int e0 = blockIdx.x * CHUNK;
  const int n = min(CHUNK, N_EDGES - e0);

  for (int b = tid; b < BINS; b += 256) lhist[b] = 0;
  __syncthreads();

  for (int i = tid; i < n; i += 256) {
    int t = etgt[e0 + i];
    stg[i] = (unsigned short)t;
    atomicAdd(&lhist[t >> 6], 1);
  }
  __syncthreads();

  for (int b = tid; b < BINS; b += 256) {
    int c = lhist[b];
    lbase[b] = c ? atomicAdd(&gcur[b], c) : 0;
    lhist[b] = 0;
  }
  __syncthreads();

  for (int i = tid; i < n; i += 256) {
    int t = (int)stg[i];
    int b = t >> 6;
    int r = atomicAdd(&lhist[b], 1);
    int pos = lbase[b] + r;
    if (pos < (b + 1) * CAPB) {
      int pack = esrc[e0 + i] | ((t & 63) << 16);
      binned[pos] = make_int2(pack, __float_as_int(eval[e0 + i]));
    }
  }
}

// ---------- kernel 2b: per-bin LDS counting sort -> per-node CSR ----------
__global__ __launch_bounds__(256) void build_csr(
    const int* __restrict__ gcur, const int2* __restrict__ binned,
    int2* __restrict__ csr, int* __restrict__ deg, int* __restrict__ rowstart)
{
  __shared__ int nh[NPB];
  __shared__ int npre[NPB];
  __shared__ __align__(16) int2 stg[CAPB];

  const int tid = threadIdx.x;
  const int b = blockIdx.x;
  const int base = b * CAPB;
  const int cnt = min(gcur[b] - base, CAPB);

  if (tid < NPB) nh[tid] = 0;
  __syncthreads();

  for (int i = tid; i < cnt; i += 256) {
    int2 e = binned[base + i];
    stg[i] = e;
    atomicAdd(&nh[(e.x >> 16) & 63], 1);
  }
  __syncthreads();

  if (tid < 64) {
    int v = nh[tid];
    int sc = v;
    #pragma unroll
    for (int off = 1; off < 64; off <<= 1) {
      int u = __shfl_up(sc, off);
      if (tid >= off) sc += u;
    }
    npre[tid] = sc - v;
    int node = b * NPB + tid;
    if (node < N_NODES) { deg[node] = v; rowstart[node] = base + sc - v; }
    nh[tid] = 0;
  }
  __syncthreads();

  for (int i = tid; i < cnt; i += 256) {
    int2 e = stg[i];
    int tl = (e.x >> 16) & 63;
    int r = atomicAdd(&nh[tl], 1);
    csr[base + npre[tl] + r] = e;
  }
}

// ---------- kernel 3: 2 nodes per wave, online-softmax + interleaved 8+8 gather ----------
__global__ __launch_bounds__(256) void aggregate_kernel(
    const int* __restrict__ deg, const int* __restrict__ rowstart,
    const int2* __restrict__ csr,
    const float* __restrict__ sbuf, const float* __restrict__ tbuf,
    const unsigned short* __restrict__ xmsg, float* __restrict__ out)
{
  const int lane = threadIdx.x & 63;
  const int wave = threadIdx.x >> 6;
  const int n0 = (blockIdx.x * 4 + wave) * 2;      // N_NODES % 8 == 0
  const int n1 = n0 + 1;

  __shared__ __align__(16) float p_lds[4][2][64][4];
  __shared__ int s_lds[4][2][64];

  const int seg  = lane & 31;
  const int half = lane >> 5;
  const int hh4  = seg >> 3;

  const int d0 = deg[n0], r0 = rowstart[n0];
  const int d1 = deg[n1], r1 = rowstart[n1];

  float4 t04 = *(const float4*)(tbuf + (size_t)n0 * 4);
  float4 t14 = *(const float4*)(tbuf + (size_t)n1 * 4);
  float tn0[4] = {t04.x, t04.y, t04.z, t04.w};
  float tn1[4] = {t14.x, t14.y, t14.z, t14.w};

  float m0[4] = {-INFINITY, -INFINITY, -INFINITY, -INFINITY};
  float m1[4] = {-INFINITY, -INFINITY, -INFINITY, -INFINITY};
  float ps0[4] = {0.f, 0.f, 0.f, 0.f};
  float ps1[4] = {0.f, 0.f, 0.f, 0.f};
  float acc0[8] = {0.f, 0.f, 0.f, 0.f, 0.f, 0.f, 0.f, 0.f};
  float acc1[8] = {0.f, 0.f, 0.f, 0.f, 0.f, 0.f, 0.f, 0.f};

  const int dmax = max(d0, d1);
  for (int base = 0; base < dmax; base += 64) {
    const int cnt0 = min(64, d0 - base);
    const int cnt1 = min(64, d1 - base);
    const bool any0 = cnt0 > 0, any1 = cnt1 > 0;
    const bool act0 = lane < cnt0, act1 = lane < cnt1;

    // ---- score phase, both nodes' load chains overlapped ----
    int2 ev0, ev1;
    if (act0) ev0 = csr[(size_t)r0 + base + lane];
    if (act1) ev1 = csr[(size_t)r1 + base + lane];
    int s0 = 0, s1 = 0;
    float4 sv40, sv41;
    if (act0) { s0 = ev0.x & 0xffff; sv40 = *(const float4*)(sbuf + (size_t)s0 * 4); }
    if (act1) { s1 = ev1.x & 0xffff; sv41 = *(const float4*)(sbuf + (size_t)s1 * 4); }

    float sc0[4] = {-INFINITY, -INFINITY, -INFINITY, -INFINITY};
    float sc1[4] = {-INFINITY, -INFINITY, -INFINITY, -INFINITY};
    if (act0) {
      float v = __int_as_float(ev0.y);
      float sw[4] = {sv40.x, sv40.y, sv40.z, sv40.w};
      #pragma unroll
      for (int hh = 0; hh < 4; ++hh) {
        float t = sw[hh] + tn0[hh];
        t = (t > 0.f) ? t : 0.01f * t;
        sc0[hh] = t * v;
      }
    }
    if (act1) {
      float v = __int_as_float(ev1.y);
      float sw[4] = {sv41.x, sv41.y, sv41.z, sv41.w};
      #pragma unroll
      for (int hh = 0; hh < 4; ++hh) {
        float t = sw[hh] + tn1[hh];
        t = (t > 0.f) ? t : 0.01f * t;
        sc1[hh] = t * v;
      }
    }

    float bm0[4] = {sc0[0], sc0[1], sc0[2], sc0[3]};
    float bm1[4] = {sc1[0], sc1[1], sc1[2], sc1[3]};
    #pragma unroll
    for (int hh = 0; hh < 4; ++hh)
      #pragma unroll
      for (int off = 32; off; off >>= 1) {
        bm0[hh] = fmaxf(bm0[hh], __shfl_xor(bm0[hh], off));
        bm1[hh] = fmaxf(bm1[hh], __shfl_xor(bm1[hh], off));
      }

    if (any0) {
      float p[4];
      #pragma unroll
      for (int hh = 0; hh < 4; ++hh) {
        float nm = fmaxf(m0[hh], bm0[hh]);
        float r = (m0[hh] == -INFINITY) ? 0.f : __expf(m0[hh] - nm);
        ps0[hh] *= r;
        if (hh == hh4) {
          #pragma unroll
          for (int j = 0; j < 8; ++j) acc0[j] *= r;
        }
        m0[hh] = nm;
        p[hh] = act0 ? __expf(sc0[hh] - nm) : 0.f;
        ps0[hh] += p[hh];
      }
      if (act0) {
        s_lds[wave][0][lane] = s0;
        *(float4*)(&p_lds[wave][0][lane][0]) = make_float4(p[0], p[1], p[2], p[3]);
      }
    }
    if (any1) {
      float p[4];
      #pragma unroll
      for (int hh = 0; hh < 4; ++hh) {
        float nm = fmaxf(m1[hh], bm1[hh]);
        float r = (m1[hh] == -INFINITY) ? 0.f : __expf(m1[hh] - nm);
        ps1[hh] *= r;
        if (hh == hh4) {
          #pragma unroll
          for (int j = 0; j < 8; ++j) acc1[j] *= r;
        }
        m1[hh] = nm;
        p[hh] = act1 ? __expf(sc1[hh] - nm) : 0.f;
        ps1[hh] += p[hh];
      }
      if (act1) {
        s_lds[wave][1][lane] = s1;
        *(float4*)(&p_lds[wave][1][lane][0]) = make_float4(p[0], p[1], p[2], p[3]);
      }
    }
    __builtin_amdgcn_wave_barrier();

    // ---- gather phase: rounds of 8 edges per node, both nodes' loads in flight ----
    const int kmax = max(max(cnt0, cnt1), 0);
    for (int k = 0; k < kmax; k += 8) {
      const bool g0 = k < cnt0, g1 = k < cnt1;      // uniform
      uint4 R0[4], R1[4];
      float Q0[4], Q1[4];
      if (g0) {
        const int c = cnt0 - 1;
        #pragma unroll
        for (int i = 0; i < 4; ++i) {
          int ii = k + 2 * i + half;
          int j = min(ii, c);
          R0[i] = *(const uint4*)(xmsg + (size_t)s_lds[wave][0][j] * CH + seg * 8);
          Q0[i] = (ii < cnt0) ? p_lds[wave][0][j][hh4] : 0.f;
        }
      }
      if (g1) {
        const int c = cnt1 - 1;
        #pragma unroll
        for (int i = 0; i < 4; ++i) {
          int ii = k + 2 * i + half;
          int j = min(ii, c);
          R1[i] = *(const uint4*)(xmsg + (size_t)s_lds[wave][1][j] * CH + seg * 8);
          Q1[i] = (ii < cnt1) ? p_lds[wave][1][j][hh4] : 0.f;
        }
      }
      if (g0) {
        #pragma unroll
        for (int i = 0; i < 4; ++i) {
          float qq = Q0[i]; uint4 rr = R0[i];
          acc0[0] = fmaf(qq, bf16_lo(rr.x), acc0[0]); acc0[1] = fmaf(qq, bf16_hi(rr.x), acc0[1]);
          acc0[2] = fmaf(qq, bf16_lo(rr.y), acc0[2]); acc0[3] = fmaf(qq, bf16_hi(rr.y), acc0[3]);
          acc0[4] = fmaf(qq, bf16_lo(rr.z), acc0[4]); acc0[5] = fmaf(qq, bf16_hi(rr.z), acc0[5]);
          acc0[6] = fmaf(qq, bf16_lo(rr.w), acc0[6]); acc0[7] = fmaf(qq, bf16_hi(rr.w), acc0[7]);
        }
      }
      if (g1) {
        #pragma unroll
        for (int i = 0; i < 4; ++i) {
          float qq = Q1[i]; uint4 rr = R1[i];
          acc1[0] = fmaf(qq, bf16_lo(rr.x), acc1[0]); acc1[1] = fmaf(qq, bf16_hi(rr.x), acc1[1]);
          acc1[2] = fmaf(qq, bf16_lo(rr.y), acc1[2]); acc1[3] = fmaf(qq, bf16_hi(rr.y), acc1[3]);
          acc1[4] = fmaf(qq, bf16_lo(rr.z), acc1[4]); acc1[5] = fmaf(qq, bf16_hi(rr.z), acc1[5]);
          acc1[6] = fmaf(qq, bf16_lo(rr.w), acc1[6]); acc1[7] = fmaf(qq, bf16_hi(rr.w), acc1[7]);
        }
      }
    }
    __builtin_amdgcn_wave_barrier();
  }

  // ---- final reductions + stores ----
  #pragma unroll
  for (int j = 0; j < 8; ++j) {
    acc0[j] += __shfl_xor(acc0[j], 32);
    acc1[j] += __shfl_xor(acc1[j], 32);
  }
  #pragma unroll
  for (int hh = 0; hh < 4; ++hh)
    #pragma unroll
    for (int off = 32; off; off >>= 1) {
      ps0[hh] += __shfl_xor(ps0[hh], off);
      ps1[hh] += __shfl_xor(ps1[hh], off);
    }

  const int o = half * 4;
  {
    float rs = ps0[hh4];
    float inv = (rs > 0.f) ? 1.0f / rs : 0.f;
    float4 o4 = make_float4(acc0[o+0]*inv, acc0[o+1]*inv, acc0[o+2]*inv, acc0[o+3]*inv);
    *(float4*)(out + (size_t)n0 * CH + seg * 8 + o) = o4;
  }
  {
    float rs = ps1[hh4];
    float inv = (rs > 0.f) ? 1.0f / rs : 0.f;
    float4 o4 = make_float4(acc1[o+0]*inv, acc1[o+1]*inv, acc1[o+2]*inv, acc1[o+3]*inv);
    *(float4*)(out + (size_t)n1 * CH + seg * 8 + o) = o4;
  }
}

// ---------- launch ----------
extern "C" void kernel_launch(void* const* d_in, const int* in_sizes, int n_in,
                              void* d_out, int out_size, void* d_ws, size_t ws_size,
                              hipStream_t stream) {
  const float* x    = (const float*)d_in[0];
  const int*   etgt = (const int*)  d_in[1];
  const int*   esrc = (const int*)  d_in[2];
  const float* evl  = (const float*)d_in[3];
  const float* w    = (const float*)d_in[4];
  const float* aw   = (const float*)d_in[5];
  float* out = (float*)d_out;

  char* ws = (char*)d_ws;
  unsigned short* wb2  = (unsigned short*)(ws);              //      65,536 B
  unsigned short* xmsg = (unsigned short*)(ws + 65536);      //  25,600,000 B
  float* sbuf     = (float*)(ws + 25665536);                 //     800,000 B
  float* tbuf     = (float*)(ws + 26465536);                 //     800,000 B
  int*   gcur     = (int*)  (ws + 27265536);                 //       4,096 B
  int*   deg      = (int*)  (ws + 27269632);                 //     200,704 B
  int*   rowstart = (int*)  (ws + 27470336);                 //     200,704 B
  int2*  binned   = (int2*) (ws + 27671040);                 //  19,218,432 B
  int2*  csr      = (int2*) (ws + 46889472);                 //  19,218,432 B

  prep_kernel<<<129, 256, 0, stream>>>(w, wb2, gcur);
  gemm_mfma<<<(N_NODES + 127) / 128, 256, 0, stream>>>(x, wb2, aw, xmsg, sbuf, tbuf);
  bin_scatter<<<(N_EDGES + CHUNK - 1) / CHUNK, 256, 0, stream>>>(etgt, esrc, evl, gcur, binned);
  build_csr<<<BINS, 256, 0, stream>>>(gcur, binned, csr, deg, rowstart);
  aggregate_kernel<<<N_NODES / 8, 256, 0, stream>>>(deg, rowstart, csr,
                                                    sbuf, tbuf, xmsg, out);
}

// Round 6
// 291.774 us; speedup vs baseline: 1.0060x; 1.0060x over previous
//
#include <hip/hip_runtime.h>
#include <hip/hip_bf16.h>
#include <hip/hip_fp16.h>
#include <math.h>

#define N_NODES 50000
#define N_EDGES 1600000
#define IN_CH   128
#define OUT_CH  64
#define N_HEADS 4
#define CH      (N_HEADS * OUT_CH)   // 256

#define NPB   64                     // nodes per bin
#define BINS  782                    // ceil(50000/64)
#define CAPB  3072                   // per-bin edge capacity (avg 2048)
#define CHUNK 4000                   // edges per bin_scatter block (400 blocks)

typedef __attribute__((ext_vector_type(8))) _Float16 f16x8;
typedef __attribute__((ext_vector_type(4))) float f32x4;

// ---------- helpers ----------
__device__ __forceinline__ __half2 u2h2(unsigned u) {
  union { unsigned u; __half2 h; } c; c.u = u; return c.h;
}

// ---------- kernel 0: prep = W swizzle (f16, A-fragment order) + cursor init ----------
// A-frag (16x16x32, A[m][k]): m = lane&15 = channel-in-block, k = (lane>>4)*8 + j.
__global__ __launch_bounds__(256) void prep_kernel(
    const float* __restrict__ w, unsigned short* __restrict__ wb2,
    int* __restrict__ gcur)
{
  if (blockIdx.x < 128) {
    int i = blockIdx.x * 256 + threadIdx.x;        // 32768 total
    int j = i & 7, lane = (i >> 3) & 63, kc = (i >> 9) & 3, mb = i >> 11;
    int k = kc * 32 + (lane >> 4) * 8 + j;
    int ch = mb * 16 + (lane & 15);
    int h = ch >> 6, o = ch & 63;
    wb2[i] = __half_as_ushort(__float2half_rn(w[(h * IN_CH + k) * OUT_CH + o]));
  } else {
    for (int b = threadIdx.x; b < BINS; b += 256) gcur[b] = b * CAPB;
  }
}

// ---------- kernel 1: f16 MFMA GEMM, swapped operands: D[ch][node] ----------
// block 256 = 4 waves; wave = 32 nodes (2 tiles of 16) x 256 channels.
__global__ __launch_bounds__(256) void gemm_mfma(
    const float* __restrict__ x, const unsigned short* __restrict__ wb2,
    const float* __restrict__ aw,
    unsigned short* __restrict__ xmsg, float* __restrict__ sbuf, float* __restrict__ tbuf)
{
  const int lane = threadIdx.x & 63;
  const int wv   = threadIdx.x >> 6;
  const int q    = lane >> 4;
  const int l16  = lane & 15;
  const int nb   = blockIdx.x * 128 + wv * 32;

  // B-frags: B[k][n], n = l16 (node), k = q*8+j; fp32 loads -> f16
  f16x8 bfrag[2][4];
  #pragma unroll
  for (int t = 0; t < 2; ++t) {
    int node = min(nb + t * 16 + l16, N_NODES - 1);
    const float* xp = x + (size_t)node * IN_CH + q * 8;
    #pragma unroll
    for (int kc = 0; kc < 4; ++kc) {
      f32x4 lo = *(const f32x4*)(xp + kc * 32);
      f32x4 hi = *(const f32x4*)(xp + kc * 32 + 4);
      f16x8 b;
      b[0] = (_Float16)lo[0]; b[1] = (_Float16)lo[1];
      b[2] = (_Float16)lo[2]; b[3] = (_Float16)lo[3];
      b[4] = (_Float16)hi[0]; b[5] = (_Float16)hi[1];
      b[6] = (_Float16)hi[2]; b[7] = (_Float16)hi[3];
      bfrag[t][kc] = b;
    }
  }

  f32x4 acc[2][16];
  #pragma unroll
  for (int t = 0; t < 2; ++t)
    #pragma unroll
    for (int mb = 0; mb < 16; ++mb)
      acc[t][mb] = (f32x4){0.f, 0.f, 0.f, 0.f};

  #pragma unroll
  for (int kc = 0; kc < 4; ++kc) {
    #pragma unroll
    for (int mb = 0; mb < 16; ++mb) {
      f16x8 a = *(const f16x8*)(wb2 + ((size_t)(mb * 4 + kc) * 64 + lane) * 8);
      acc[0][mb] = __builtin_amdgcn_mfma_f32_16x16x32_f16(a, bfrag[0][kc], acc[0][mb], 0, 0, 0);
      acc[1][mb] = __builtin_amdgcn_mfma_f32_16x16x32_f16(a, bfrag[1][kc], acc[1][mb], 0, 0, 0);
    }
  }

  // epilogue: lane owns node (l16) x channels {mb*16 + q*4 + reg}
  #pragma unroll
  for (int t = 0; t < 2; ++t) {
    const int node = nb + t * 16 + l16;
    const bool valid = node < N_NODES;

    float sv[4] = {0.f, 0.f, 0.f, 0.f};
    float tv[4] = {0.f, 0.f, 0.f, 0.f};
    #pragma unroll
    for (int mb = 0; mb < 16; ++mb) {
      ushort4 pk;
      pk.x = __half_as_ushort(__float2half_rn(acc[t][mb][0]));
      pk.y = __half_as_ushort(__float2half_rn(acc[t][mb][1]));
      pk.z = __half_as_ushort(__float2half_rn(acc[t][mb][2]));
      pk.w = __half_as_ushort(__float2half_rn(acc[t][mb][3]));
      if (valid)
        *(ushort4*)(xmsg + (size_t)node * CH + mb * 16 + q * 4) = pk;

      const int h = mb >> 2;
      const int o = (mb & 3) * 16 + q * 4;
      #pragma unroll
      for (int reg = 0; reg < 4; ++reg) {
        float as_ = aw[h * 128 + o + reg];
        float at_ = aw[h * 128 + 64 + o + reg];
        sv[h] += acc[t][mb][reg] * as_;
        tv[h] += acc[t][mb][reg] * at_;
      }
    }
    #pragma unroll
    for (int hh = 0; hh < 4; ++hh) {
      sv[hh] += __shfl_xor(sv[hh], 16); sv[hh] += __shfl_xor(sv[hh], 32);
      tv[hh] += __shfl_xor(tv[hh], 16); tv[hh] += __shfl_xor(tv[hh], 32);
    }
    float svq = (q == 0) ? sv[0] : (q == 1) ? sv[1] : (q == 2) ? sv[2] : sv[3];
    float tvq = (q == 0) ? tv[0] : (q == 1) ? tv[1] : (q == 2) ? tv[2] : tv[3];
    if (valid) {
      sbuf[node * 4 + q] = svq;
      tbuf[node * 4 + q] = tvq;
    }
  }
}

// ---------- kernel 2a: binned ranked scatter ----------
__global__ __launch_bounds__(256) void bin_scatter(
    const int* __restrict__ etgt, const int* __restrict__ esrc,
    const float* __restrict__ eval, int* __restrict__ gcur, int2* __restrict__ binned)
{
  __shared__ int lhist[BINS];
  __shared__ int lbase[BINS];
  __shared__ unsigned short stg[CHUNK];

  const int tid = threadIdx.x;
  const int e0 = blockIdx.x * CHUNK;
  const int n = min(CHUNK, N_EDGES - e0);

  for (int b = tid; b < BINS; b += 256) lhist[b] = 0;
  __syncthreads();

  for (int i = tid; i < n; i += 256) {
    int t = etgt[e0 + i];
    stg[i] = (unsigned short)t;
    atomicAdd(&lhist[t >> 6], 1);
  }
  __syncthreads();

  for (int b = tid; b < BINS; b += 256) {
    int c = lhist[b];
    lbase[b] = c ? atomicAdd(&gcur[b], c) : 0;
    lhist[b] = 0;
  }
  __syncthreads();

  for (int i = tid; i < n; i += 256) {
    int t = (int)stg[i];
    int b = t >> 6;
    int r = atomicAdd(&lhist[b], 1);
    int pos = lbase[b] + r;
    if (pos < (b + 1) * CAPB) {
      int pack = esrc[e0 + i] | ((t & 63) << 16);
      binned[pos] = make_int2(pack, __float_as_int(eval[e0 + i]));
    }
  }
}

// ---------- kernel 2b: per-bin LDS counting sort -> per-node CSR ----------
__global__ __launch_bounds__(256) void build_csr(
    const int* __restrict__ gcur, const int2* __restrict__ binned,
    int2* __restrict__ csr, int* __restrict__ deg, int* __restrict__ rowstart)
{
  __shared__ int nh[NPB];
  __shared__ int npre[NPB];
  __shared__ __align__(16) int2 stg[CAPB];

  const int tid = threadIdx.x;
  const int b = blockIdx.x;
  const int base = b * CAPB;
  const int cnt = min(gcur[b] - base, CAPB);

  if (tid < NPB) nh[tid] = 0;
  __syncthreads();

  for (int i = tid; i < cnt; i += 256) {
    int2 e = binned[base + i];
    stg[i] = e;
    atomicAdd(&nh[(e.x >> 16) & 63], 1);
  }
  __syncthreads();

  if (tid < 64) {
    int v = nh[tid];
    int sc = v;
    #pragma unroll
    for (int off = 1; off < 64; off <<= 1) {
      int u = __shfl_up(sc, off);
      if (tid >= off) sc += u;
    }
    npre[tid] = sc - v;
    int node = b * NPB + tid;
    if (node < N_NODES) { deg[node] = v; rowstart[node] = base + sc - v; }
    nh[tid] = 0;
  }
  __syncthreads();

  for (int i = tid; i < cnt; i += 256) {
    int2 e = stg[i];
    int tl = (e.x >> 16) & 63;
    int r = atomicAdd(&nh[tl], 1);
    csr[base + npre[tl] + r] = e;
  }
}

// ---------- kernel 3: one wave per node, online-softmax + packed-f16 gather ----------
__global__ __launch_bounds__(256) void aggregate_kernel(
    const int* __restrict__ deg, const int* __restrict__ rowstart,
    const int2* __restrict__ csr,
    const float* __restrict__ sbuf, const float* __restrict__ tbuf,
    const unsigned short* __restrict__ xmsg, float* __restrict__ out)
{
  const int lane = threadIdx.x & 63;
  const int wave = threadIdx.x >> 6;
  const int n = blockIdx.x * 4 + wave;
  if (n >= N_NODES) return;

  __shared__ __align__(16) float p_lds[4][64][4];
  __shared__ int s_lds[4][64];

  const int d = deg[n];
  const int rs0 = rowstart[n];
  const int seg  = lane & 31;
  const int half = lane >> 5;
  const int hh4  = seg >> 3;          // head of this lane's 8 channels

  float4 tn4 = *(const float4*)(tbuf + (size_t)n * 4);
  float tn[4] = {tn4.x, tn4.y, tn4.z, tn4.w};

  float m[4]    = {-INFINITY, -INFINITY, -INFINITY, -INFINITY};
  float psum[4] = {0.f, 0.f, 0.f, 0.f};
  __half2 hacc[4];
  #pragma unroll
  for (int j = 0; j < 4; ++j) hacc[j] = __float2half2_rn(0.f);

  for (int base = 0; base < d; base += 64) {
    const int cnt = min(64, d - base);
    const bool act = lane < cnt;

    float sc[4] = {-INFINITY, -INFINITY, -INFINITY, -INFINITY};
    int s = 0;
    if (act) {
      int2 ev = csr[(size_t)rs0 + base + lane];
      s = ev.x & 0xffff;
      float v = __int_as_float(ev.y);
      float4 sv4 = *(const float4*)(sbuf + (size_t)s * 4);
      float svv[4] = {sv4.x, sv4.y, sv4.z, sv4.w};
      #pragma unroll
      for (int hh = 0; hh < 4; ++hh) {
        float t = svv[hh] + tn[hh];
        t = (t > 0.f) ? t : 0.01f * t;           // leaky_relu
        sc[hh] = t * v;
      }
    }

    float bm[4] = {sc[0], sc[1], sc[2], sc[3]};
    #pragma unroll
    for (int hh = 0; hh < 4; ++hh)
      #pragma unroll
      for (int off = 32; off; off >>= 1)
        bm[hh] = fmaxf(bm[hh], __shfl_xor(bm[hh], off));

    float p[4];
    #pragma unroll
    for (int hh = 0; hh < 4; ++hh) {
      float nm = fmaxf(m[hh], bm[hh]);
      float r = (m[hh] == -INFINITY) ? 0.f : __expf(m[hh] - nm);
      psum[hh] *= r;
      if (hh == hh4) {
        __half2 rh = __float2half2_rn(r);
        #pragma unroll
        for (int j = 0; j < 4; ++j) hacc[j] = __hmul2(hacc[j], rh);
      }
      m[hh] = nm;
      p[hh] = act ? __expf(sc[hh] - nm) : 0.f;
      psum[hh] += p[hh];
    }

    if (act) {
      s_lds[wave][lane] = s;
      *(float4*)(&p_lds[wave][lane][0]) = make_float4(p[0], p[1], p[2], p[3]);
    }
    __builtin_amdgcn_wave_barrier();

    int k = 0;
    for (; k + 8 <= cnt; k += 8) {
      int sA = s_lds[wave][k + 0 + half];
      int sB = s_lds[wave][k + 2 + half];
      int sC = s_lds[wave][k + 4 + half];
      int sD = s_lds[wave][k + 6 + half];
      uint4 rA = *(const uint4*)(xmsg + (size_t)sA * CH + seg * 8);
      uint4 rB = *(const uint4*)(xmsg + (size_t)sB * CH + seg * 8);
      uint4 rC = *(const uint4*)(xmsg + (size_t)sC * CH + seg * 8);
      uint4 rD = *(const uint4*)(xmsg + (size_t)sD * CH + seg * 8);
      __half2 qA = __float2half2_rn(p_lds[wave][k + 0 + half][hh4]);
      __half2 qB = __float2half2_rn(p_lds[wave][k + 2 + half][hh4]);
      __half2 qC = __float2half2_rn(p_lds[wave][k + 4 + half][hh4]);
      __half2 qD = __float2half2_rn(p_lds[wave][k + 6 + half][hh4]);
      hacc[0] = __hfma2(qA, u2h2(rA.x), hacc[0]);
      hacc[1] = __hfma2(qA, u2h2(rA.y), hacc[1]);
      hacc[2] = __hfma2(qA, u2h2(rA.z), hacc[2]);
      hacc[3] = __hfma2(qA, u2h2(rA.w), hacc[3]);
      hacc[0] = __hfma2(qB, u2h2(rB.x), hacc[0]);
      hacc[1] = __hfma2(qB, u2h2(rB.y), hacc[1]);
      hacc[2] = __hfma2(qB, u2h2(rB.z), hacc[2]);
      hacc[3] = __hfma2(qB, u2h2(rB.w), hacc[3]);
      hacc[0] = __hfma2(qC, u2h2(rC.x), hacc[0]);
      hacc[1] = __hfma2(qC, u2h2(rC.y), hacc[1]);
      hacc[2] = __hfma2(qC, u2h2(rC.z), hacc[2]);
      hacc[3] = __hfma2(qC, u2h2(rC.w), hacc[3]);
      hacc[0] = __hfma2(qD, u2h2(rD.x), hacc[0]);
      hacc[1] = __hfma2(qD, u2h2(rD.y), hacc[1]);
      hacc[2] = __hfma2(qD, u2h2(rD.z), hacc[2]);
      hacc[3] = __hfma2(qD, u2h2(rD.w), hacc[3]);
    }
    for (; k < cnt; k += 2) {
      int e = k + half;
      if (e < cnt) {
        int sA = s_lds[wave][e];
        uint4 rA = *(const uint4*)(xmsg + (size_t)sA * CH + seg * 8);
        __half2 qA = __float2half2_rn(p_lds[wave][e][hh4]);
        hacc[0] = __hfma2(qA, u2h2(rA.x), hacc[0]);
        hacc[1] = __hfma2(qA, u2h2(rA.y), hacc[1]);
        hacc[2] = __hfma2(qA, u2h2(rA.z), hacc[2]);
        hacc[3] = __hfma2(qA, u2h2(rA.w), hacc[3]);
      }
    }
    __builtin_amdgcn_wave_barrier();
  }

  float acc[8];
  #pragma unroll
  for (int j = 0; j < 4; ++j) {
    acc[2*j]   = __low2float(hacc[j]);
    acc[2*j+1] = __high2float(hacc[j]);
  }
  #pragma unroll
  for (int j = 0; j < 8; ++j) acc[j] += __shfl_xor(acc[j], 32);
  #pragma unroll
  for (int hh = 0; hh < 4; ++hh)
    #pragma unroll
    for (int off = 32; off; off >>= 1)
      psum[hh] += __shfl_xor(psum[hh], off);

  float rs = psum[hh4];
  float inv = (rs > 0.f) ? 1.0f / rs : 0.f;
  const int o = half * 4;
  float4 o4 = make_float4(acc[o+0]*inv, acc[o+1]*inv, acc[o+2]*inv, acc[o+3]*inv);
  *(float4*)(out + (size_t)n * CH + seg * 8 + o) = o4;
}

// ---------- launch ----------
extern "C" void kernel_launch(void* const* d_in, const int* in_sizes, int n_in,
                              void* d_out, int out_size, void* d_ws, size_t ws_size,
                              hipStream_t stream) {
  const float* x    = (const float*)d_in[0];
  const int*   etgt = (const int*)  d_in[1];
  const int*   esrc = (const int*)  d_in[2];
  const float* evl  = (const float*)d_in[3];
  const float* w    = (const float*)d_in[4];
  const float* aw   = (const float*)d_in[5];
  float* out = (float*)d_out;

  char* ws = (char*)d_ws;
  unsigned short* wb2  = (unsigned short*)(ws);              //      65,536 B
  unsigned short* xmsg = (unsigned short*)(ws + 65536);      //  25,600,000 B
  float* sbuf     = (float*)(ws + 25665536);                 //     800,000 B
  float* tbuf     = (float*)(ws + 26465536);                 //     800,000 B
  int*   gcur     = (int*)  (ws + 27265536);                 //       4,096 B
  int*   deg      = (int*)  (ws + 27269632);                 //     200,704 B
  int*   rowstart = (int*)  (ws + 27470336);                 //     200,704 B
  int2*  binned   = (int2*) (ws + 27671040);                 //  19,218,432 B
  int2*  csr      = (int2*) (ws + 46889472);                 //  19,218,432 B

  prep_kernel<<<129, 256, 0, stream>>>(w, wb2, gcur);
  gemm_mfma<<<(N_NODES + 127) / 128, 256, 0, stream>>>(x, wb2, aw, xmsg, sbuf, tbuf);
  bin_scatter<<<(N_EDGES + CHUNK - 1) / CHUNK, 256, 0, stream>>>(etgt, esrc, evl, gcur, binned);
  build_csr<<<BINS, 256, 0, stream>>>(gcur, binned, csr, deg, rowstart);
  aggregate_kernel<<<(N_NODES + 3) / 4, 256, 0, stream>>>(deg, rowstart, csr,
                                                          sbuf, tbuf, xmsg, out);
}

// Round 7
// 291.553 us; speedup vs baseline: 1.0067x; 1.0008x over previous
//
#include <hip/hip_runtime.h>
#include <hip/hip_bf16.h>
#include <hip/hip_fp16.h>
#include <math.h>

#define N_NODES 50000
#define N_EDGES 1600000
#define IN_CH   128
#define OUT_CH  64
#define N_HEADS 4
#define CH      (N_HEADS * OUT_CH)   // 256

#define NPB   32                     // nodes per bin
#define BINS  1563                   // ceil(50000/32)
#define CAPB  1280                   // per-bin edge capacity (avg 1024, sigma~32, 8-sigma slack)
#define CHUNK 4000                   // edges per bin_scatter block (400 blocks)

typedef __attribute__((ext_vector_type(8))) _Float16 f16x8;
typedef __attribute__((ext_vector_type(4))) float f32x4;

// ---------- helpers ----------
__device__ __forceinline__ __half2 u2h2(unsigned u) {
  union { unsigned u; __half2 h; } c; c.u = u; return c.h;
}

// ---------- kernel 0: prep = W swizzle (f16, A-fragment order) + cursor init ----------
__global__ __launch_bounds__(256) void prep_kernel(
    const float* __restrict__ w, unsigned short* __restrict__ wb2,
    int* __restrict__ gcur)
{
  if (blockIdx.x < 128) {
    int i = blockIdx.x * 256 + threadIdx.x;        // 32768 total
    int j = i & 7, lane = (i >> 3) & 63, kc = (i >> 9) & 3, mb = i >> 11;
    int k = kc * 32 + (lane >> 4) * 8 + j;
    int ch = mb * 16 + (lane & 15);
    int h = ch >> 6, o = ch & 63;
    wb2[i] = __half_as_ushort(__float2half_rn(w[(h * IN_CH + k) * OUT_CH + o]));
  } else {
    for (int b = threadIdx.x; b < BINS; b += 256) gcur[b] = b * CAPB;
  }
}

// ---------- kernel 1: f16 MFMA GEMM, swapped operands: D[ch][node] ----------
__global__ __launch_bounds__(256) void gemm_mfma(
    const float* __restrict__ x, const unsigned short* __restrict__ wb2,
    const float* __restrict__ aw,
    unsigned short* __restrict__ xmsg, float* __restrict__ sbuf, float* __restrict__ tbuf)
{
  const int lane = threadIdx.x & 63;
  const int wv   = threadIdx.x >> 6;
  const int q    = lane >> 4;
  const int l16  = lane & 15;
  const int nb   = blockIdx.x * 128 + wv * 32;

  f16x8 bfrag[2][4];
  #pragma unroll
  for (int t = 0; t < 2; ++t) {
    int node = min(nb + t * 16 + l16, N_NODES - 1);
    const float* xp = x + (size_t)node * IN_CH + q * 8;
    #pragma unroll
    for (int kc = 0; kc < 4; ++kc) {
      f32x4 lo = *(const f32x4*)(xp + kc * 32);
      f32x4 hi = *(const f32x4*)(xp + kc * 32 + 4);
      f16x8 b;
      b[0] = (_Float16)lo[0]; b[1] = (_Float16)lo[1];
      b[2] = (_Float16)lo[2]; b[3] = (_Float16)lo[3];
      b[4] = (_Float16)hi[0]; b[5] = (_Float16)hi[1];
      b[6] = (_Float16)hi[2]; b[7] = (_Float16)hi[3];
      bfrag[t][kc] = b;
    }
  }

  f32x4 acc[2][16];
  #pragma unroll
  for (int t = 0; t < 2; ++t)
    #pragma unroll
    for (int mb = 0; mb < 16; ++mb)
      acc[t][mb] = (f32x4){0.f, 0.f, 0.f, 0.f};

  #pragma unroll
  for (int kc = 0; kc < 4; ++kc) {
    #pragma unroll
    for (int mb = 0; mb < 16; ++mb) {
      f16x8 a = *(const f16x8*)(wb2 + ((size_t)(mb * 4 + kc) * 64 + lane) * 8);
      acc[0][mb] = __builtin_amdgcn_mfma_f32_16x16x32_f16(a, bfrag[0][kc], acc[0][mb], 0, 0, 0);
      acc[1][mb] = __builtin_amdgcn_mfma_f32_16x16x32_f16(a, bfrag[1][kc], acc[1][mb], 0, 0, 0);
    }
  }

  #pragma unroll
  for (int t = 0; t < 2; ++t) {
    const int node = nb + t * 16 + l16;
    const bool valid = node < N_NODES;

    float sv[4] = {0.f, 0.f, 0.f, 0.f};
    float tv[4] = {0.f, 0.f, 0.f, 0.f};
    #pragma unroll
    for (int mb = 0; mb < 16; ++mb) {
      ushort4 pk;
      pk.x = __half_as_ushort(__float2half_rn(acc[t][mb][0]));
      pk.y = __half_as_ushort(__float2half_rn(acc[t][mb][1]));
      pk.z = __half_as_ushort(__float2half_rn(acc[t][mb][2]));
      pk.w = __half_as_ushort(__float2half_rn(acc[t][mb][3]));
      if (valid)
        *(ushort4*)(xmsg + (size_t)node * CH + mb * 16 + q * 4) = pk;

      const int h = mb >> 2;
      const int o = (mb & 3) * 16 + q * 4;
      #pragma unroll
      for (int reg = 0; reg < 4; ++reg) {
        float as_ = aw[h * 128 + o + reg];
        float at_ = aw[h * 128 + 64 + o + reg];
        sv[h] += acc[t][mb][reg] * as_;
        tv[h] += acc[t][mb][reg] * at_;
      }
    }
    #pragma unroll
    for (int hh = 0; hh < 4; ++hh) {
      sv[hh] += __shfl_xor(sv[hh], 16); sv[hh] += __shfl_xor(sv[hh], 32);
      tv[hh] += __shfl_xor(tv[hh], 16); tv[hh] += __shfl_xor(tv[hh], 32);
    }
    float svq = (q == 0) ? sv[0] : (q == 1) ? sv[1] : (q == 2) ? sv[2] : sv[3];
    float tvq = (q == 0) ? tv[0] : (q == 1) ? tv[1] : (q == 2) ? tv[2] : tv[3];
    if (valid) {
      sbuf[node * 4 + q] = svq;
      tbuf[node * 4 + q] = tvq;
    }
  }
}

// ---------- kernel 2: binned ranked scatter ----------
// entry: {src | tgt_local<<16, eval_bits}, tgt_local = t & 31
__global__ __launch_bounds__(256) void bin_scatter(
    const int* __restrict__ etgt, const int* __restrict__ esrc,
    const float* __restrict__ eval, int* __restrict__ gcur, int2* __restrict__ binned)
{
  __shared__ int lhist[BINS];
  __shared__ int lbase[BINS];
  __shared__ unsigned short stg[CHUNK];

  const int tid = threadIdx.x;
  const int e0 = blockIdx.x * CHUNK;
  const int n = min(CHUNK, N_EDGES - e0);

  for (int b = tid; b < BINS; b += 256) lhist[b] = 0;
  __syncthreads();

  for (int i = tid; i < n; i += 256) {
    int t = etgt[e0 + i];
    stg[i] = (unsigned short)t;
    atomicAdd(&lhist[t >> 5], 1);
  }
  __syncthreads();

  for (int b = tid; b < BINS; b += 256) {
    int c = lhist[b];
    lbase[b] = c ? atomicAdd(&gcur[b], c) : 0;
    lhist[b] = 0;
  }
  __syncthreads();

  for (int i = tid; i < n; i += 256) {
    int t = (int)stg[i];
    int b = t >> 5;
    int r = atomicAdd(&lhist[b], 1);
    int pos = lbase[b] + r;
    if (pos < (b + 1) * CAPB) {
      int pack = esrc[e0 + i] | ((t & 31) << 16);
      binned[pos] = make_int2(pack, __float_as_int(eval[e0 + i]));
    }
  }
}

// ---------- kernel 3: fused CSR-build + aggregate; block = bin of 32 nodes ----------
// Phase A: LDS counting sort of the bin's edges (two contiguous global reads).
// Phase B: each of 4 waves processes 8 nodes: online-softmax + packed-f16 gather.
__global__ __launch_bounds__(256) void aggregate_fused(
    const int* __restrict__ gcur, const int2* __restrict__ binned,
    const float* __restrict__ sbuf, const float* __restrict__ tbuf,
    const unsigned short* __restrict__ xmsg, float* __restrict__ out)
{
  __shared__ __align__(16) int2 s2[CAPB];          // sorted edges {pack, eval}
  __shared__ int nh[NPB];
  __shared__ int npre[NPB];
  __shared__ __align__(16) float p_lds[4][64][4];

  const int tid = threadIdx.x;
  const int b = blockIdx.x;
  const int base = b * CAPB;
  const int cnt = min(gcur[b] - base, CAPB);

  if (tid < NPB) nh[tid] = 0;
  __syncthreads();

  // pass 1: histogram (contiguous read)
  for (int i = tid; i < cnt; i += 256)
    atomicAdd(&nh[(binned[base + i].x >> 16) & 31], 1);
  __syncthreads();

  // exclusive prefix over 32 counters (lanes 0..31 of wave 0)
  if (tid < NPB) {
    int v = nh[tid];
    int sc = v;
    #pragma unroll
    for (int off = 1; off < NPB; off <<= 1) {
      int u = __shfl_up(sc, off);
      if (tid >= off) sc += u;
    }
    npre[tid] = sc - v;
    nh[tid] = 0;                      // reuse as rank counter
  }
  __syncthreads();

  // pass 2: rank-scatter into sorted LDS (second contiguous read)
  for (int i = tid; i < cnt; i += 256) {
    int2 e = binned[base + i];
    int tl = (e.x >> 16) & 31;
    int r = atomicAdd(&nh[tl], 1);
    s2[npre[tl] + r] = e;
  }
  __syncthreads();                     // nh[tl] == deg now

  const int lane = tid & 63;
  const int wave = tid >> 6;
  const int seg  = lane & 31;
  const int half = lane >> 5;
  const int hh4  = seg >> 3;           // head of this lane's 8 channels

  for (int nn = 0; nn < 8; ++nn) {
    const int tl = wave * 8 + nn;
    const int n = b * NPB + tl;
    if (n >= N_NODES) break;           // wave-uniform

    const int d = nh[tl];
    const int rs0 = npre[tl];

    float4 tn4 = *(const float4*)(tbuf + (size_t)n * 4);
    float tn[4] = {tn4.x, tn4.y, tn4.z, tn4.w};

    float m[4]    = {-INFINITY, -INFINITY, -INFINITY, -INFINITY};
    float psum[4] = {0.f, 0.f, 0.f, 0.f};
    __half2 hacc[4];
    #pragma unroll
    for (int j = 0; j < 4; ++j) hacc[j] = __float2half2_rn(0.f);

    for (int bb = 0; bb < d; bb += 64) {
      const int cnt2 = min(64, d - bb);
      const bool act = lane < cnt2;

      float sc[4] = {-INFINITY, -INFINITY, -INFINITY, -INFINITY};
      if (act) {
        int2 ev = s2[rs0 + bb + lane];
        int s = ev.x & 0xffff;
        float v = __int_as_float(ev.y);
        float4 sv4 = *(const float4*)(sbuf + (size_t)s * 4);
        float svv[4] = {sv4.x, sv4.y, sv4.z, sv4.w};
        #pragma unroll
        for (int hh = 0; hh < 4; ++hh) {
          float t = svv[hh] + tn[hh];
          t = (t > 0.f) ? t : 0.01f * t;         // leaky_relu
          sc[hh] = t * v;
        }
      }

      float bm[4] = {sc[0], sc[1], sc[2], sc[3]};
      #pragma unroll
      for (int hh = 0; hh < 4; ++hh)
        #pragma unroll
        for (int off = 32; off; off >>= 1)
          bm[hh] = fmaxf(bm[hh], __shfl_xor(bm[hh], off));

      float p[4];
      #pragma unroll
      for (int hh = 0; hh < 4; ++hh) {
        float nm = fmaxf(m[hh], bm[hh]);
        float r = (m[hh] == -INFINITY) ? 0.f : __expf(m[hh] - nm);
        psum[hh] *= r;
        if (hh == hh4) {
          __half2 rh = __float2half2_rn(r);
          #pragma unroll
          for (int j = 0; j < 4; ++j) hacc[j] = __hmul2(hacc[j], rh);
        }
        m[hh] = nm;
        p[hh] = act ? __expf(sc[hh] - nm) : 0.f;
        psum[hh] += p[hh];
      }

      if (act)
        *(float4*)(&p_lds[wave][lane][0]) = make_float4(p[0], p[1], p[2], p[3]);
      __builtin_amdgcn_wave_barrier();

      int k = 0;
      for (; k + 8 <= cnt2; k += 8) {
        int sA = s2[rs0 + bb + k + 0 + half].x & 0xffff;
        int sB = s2[rs0 + bb + k + 2 + half].x & 0xffff;
        int sC = s2[rs0 + bb + k + 4 + half].x & 0xffff;
        int sD = s2[rs0 + bb + k + 6 + half].x & 0xffff;
        uint4 rA = *(const uint4*)(xmsg + (size_t)sA * CH + seg * 8);
        uint4 rB = *(const uint4*)(xmsg + (size_t)sB * CH + seg * 8);
        uint4 rC = *(const uint4*)(xmsg + (size_t)sC * CH + seg * 8);
        uint4 rD = *(const uint4*)(xmsg + (size_t)sD * CH + seg * 8);
        __half2 qA = __float2half2_rn(p_lds[wave][k + 0 + half][hh4]);
        __half2 qB = __float2half2_rn(p_lds[wave][k + 2 + half][hh4]);
        __half2 qC = __float2half2_rn(p_lds[wave][k + 4 + half][hh4]);
        __half2 qD = __float2half2_rn(p_lds[wave][k + 6 + half][hh4]);
        hacc[0] = __hfma2(qA, u2h2(rA.x), hacc[0]);
        hacc[1] = __hfma2(qA, u2h2(rA.y), hacc[1]);
        hacc[2] = __hfma2(qA, u2h2(rA.z), hacc[2]);
        hacc[3] = __hfma2(qA, u2h2(rA.w), hacc[3]);
        hacc[0] = __hfma2(qB, u2h2(rB.x), hacc[0]);
        hacc[1] = __hfma2(qB, u2h2(rB.y), hacc[1]);
        hacc[2] = __hfma2(qB, u2h2(rB.z), hacc[2]);
        hacc[3] = __hfma2(qB, u2h2(rB.w), hacc[3]);
        hacc[0] = __hfma2(qC, u2h2(rC.x), hacc[0]);
        hacc[1] = __hfma2(qC, u2h2(rC.y), hacc[1]);
        hacc[2] = __hfma2(qC, u2h2(rC.z), hacc[2]);
        hacc[3] = __hfma2(qC, u2h2(rC.w), hacc[3]);
        hacc[0] = __hfma2(qD, u2h2(rD.x), hacc[0]);
        hacc[1] = __hfma2(qD, u2h2(rD.y), hacc[1]);
        hacc[2] = __hfma2(qD, u2h2(rD.z), hacc[2]);
        hacc[3] = __hfma2(qD, u2h2(rD.w), hacc[3]);
      }
      for (; k < cnt2; k += 2) {
        int e = k + half;
        if (e < cnt2) {
          int sA = s2[rs0 + bb + e].x & 0xffff;
          uint4 rA = *(const uint4*)(xmsg + (size_t)sA * CH + seg * 8);
          __half2 qA = __float2half2_rn(p_lds[wave][e][hh4]);
          hacc[0] = __hfma2(qA, u2h2(rA.x), hacc[0]);
          hacc[1] = __hfma2(qA, u2h2(rA.y), hacc[1]);
          hacc[2] = __hfma2(qA, u2h2(rA.z), hacc[2]);
          hacc[3] = __hfma2(qA, u2h2(rA.w), hacc[3]);
        }
      }
      __builtin_amdgcn_wave_barrier();
    }

    float acc[8];
    #pragma unroll
    for (int j = 0; j < 4; ++j) {
      acc[2*j]   = __low2float(hacc[j]);
      acc[2*j+1] = __high2float(hacc[j]);
    }
    #pragma unroll
    for (int j = 0; j < 8; ++j) acc[j] += __shfl_xor(acc[j], 32);
    #pragma unroll
    for (int hh = 0; hh < 4; ++hh)
      #pragma unroll
      for (int off = 32; off; off >>= 1)
        psum[hh] += __shfl_xor(psum[hh], off);

    float rs = psum[hh4];
    float inv = (rs > 0.f) ? 1.0f / rs : 0.f;
    const int o = half * 4;
    float4 o4 = make_float4(acc[o+0]*inv, acc[o+1]*inv, acc[o+2]*inv, acc[o+3]*inv);
    *(float4*)(out + (size_t)n * CH + seg * 8 + o) = o4;
  }
}

// ---------- launch ----------
extern "C" void kernel_launch(void* const* d_in, const int* in_sizes, int n_in,
                              void* d_out, int out_size, void* d_ws, size_t ws_size,
                              hipStream_t stream) {
  const float* x    = (const float*)d_in[0];
  const int*   etgt = (const int*)  d_in[1];
  const int*   esrc = (const int*)  d_in[2];
  const float* evl  = (const float*)d_in[3];
  const float* w    = (const float*)d_in[4];
  const float* aw   = (const float*)d_in[5];
  float* out = (float*)d_out;

  char* ws = (char*)d_ws;
  unsigned short* wb2  = (unsigned short*)(ws);              //      65,536 B
  unsigned short* xmsg = (unsigned short*)(ws + 65536);      //  25,600,000 B
  float* sbuf     = (float*)(ws + 25665536);                 //     800,000 B
  float* tbuf     = (float*)(ws + 26465536);                 //     800,000 B
  int*   gcur     = (int*)  (ws + 27265536);                 //       8,192 B
  int2*  binned   = (int2*) (ws + 27273728);                 //  16,005,120 B
  // total: 43,278,848 B

  prep_kernel<<<129, 256, 0, stream>>>(w, wb2, gcur);
  gemm_mfma<<<(N_NODES + 127) / 128, 256, 0, stream>>>(x, wb2, aw, xmsg, sbuf, tbuf);
  bin_scatter<<<(N_EDGES + CHUNK - 1) / CHUNK, 256, 0, stream>>>(etgt, esrc, evl, gcur, binned);
  aggregate_fused<<<BINS, 256, 0, stream>>>(gcur, binned, sbuf, tbuf, xmsg, out);
}